// Round 3
// baseline (317.838 us; speedup 1.0000x reference)
//
#include <hip/hip_runtime.h>
#include <hip/hip_cooperative_groups.h>

namespace cg = cooperative_groups;

#define HID 2048
#define NBLK (HID / 2)   // 1024 blocks = 4 blocks/CU on 256 CUs (co-resident)

typedef __attribute__((ext_vector_type(4))) float f32x4;

__device__ __forceinline__ float sigmoidf_(float x) {
    return 1.0f / (1.0f + __expf(-x));
}

// One phase: this block computes h_out[j0] and h_out[j0+1] (j0 = 2*blockIdx).
// h0 = c0 = 0  =>  W_hh unused, f-gate dead:
//   h[j] = sigmoid(g_o) * tanh( sigmoid(g_i) * tanh(g_g) )
template <int K>
__device__ __forceinline__ void layer_phase(
    const float* __restrict__ W,     // [4*HID, K]
    const float* __restrict__ b_ih,  // [4*HID]
    const float* __restrict__ b_hh,  // [4*HID]
    const float* __restrict__ xin,   // [K]
    float* __restrict__ h_out,       // [HID]
    float (*red)[4])
{
    const int t    = threadIdx.x;
    const int lane = t & 63;
    const int wv   = t >> 6;
    const int j0   = blockIdx.x * 2;

    // rows: neuron j0 {i,g,o}, neuron j0+1 {i,g,o}
    const float* rp[6];
    rp[0] = W + (size_t)j0 * K;
    rp[1] = W + (size_t)(j0 + 2 * HID) * K;
    rp[2] = W + (size_t)(j0 + 3 * HID) * K;
    rp[3] = W + (size_t)(j0 + 1) * K;
    rp[4] = W + (size_t)(j0 + 1 + 2 * HID) * K;
    rp[5] = W + (size_t)(j0 + 1 + 3 * HID) * K;

    float acc[6] = {0.f, 0.f, 0.f, 0.f, 0.f, 0.f};

    #pragma unroll
    for (int c = 0; c < K / 1024; ++c) {
        const int off = c * 1024 + t * 4;      // 16B/lane, coalesced
        f32x4 xv = *reinterpret_cast<const f32x4*>(xin + off);
        #pragma unroll
        for (int r = 0; r < 6; ++r) {
            f32x4 w = *reinterpret_cast<const f32x4*>(rp[r] + off);
            acc[r] = fmaf(w.x, xv.x, acc[r]);
            acc[r] = fmaf(w.y, xv.y, acc[r]);
            acc[r] = fmaf(w.z, xv.z, acc[r]);
            acc[r] = fmaf(w.w, xv.w, acc[r]);
        }
    }

    #pragma unroll
    for (int m = 32; m > 0; m >>= 1) {
        #pragma unroll
        for (int r = 0; r < 6; ++r) acc[r] += __shfl_xor(acc[r], m, 64);
    }

    if (lane == 0) {
        #pragma unroll
        for (int r = 0; r < 6; ++r) red[r][wv] = acc[r];
    }
    __syncthreads();

    if (t < 2) {                                // thread t finalizes neuron j0+t
        const int j = j0 + t;
        const int b = t * 3;
        const float gi = red[b+0][0] + red[b+0][1] + red[b+0][2] + red[b+0][3]
                       + b_ih[j]           + b_hh[j];
        const float gg = red[b+1][0] + red[b+1][1] + red[b+1][2] + red[b+1][3]
                       + b_ih[j + 2*HID]   + b_hh[j + 2*HID];
        const float go = red[b+2][0] + red[b+2][1] + red[b+2][2] + red[b+2][3]
                       + b_ih[j + 3*HID]   + b_hh[j + 3*HID];
        h_out[j] = sigmoidf_(go) * tanhf(sigmoidf_(gi) * tanhf(gg));
    }
}

__global__ __launch_bounds__(256, 4) void fused_lstm(
    const float* __restrict__ x,
    const float* __restrict__ Wih0, const float* __restrict__ bih0, const float* __restrict__ bhh0,
    const float* __restrict__ Wih1, const float* __restrict__ bih1, const float* __restrict__ bhh1,
    const float* __restrict__ Wih2, const float* __restrict__ bih2, const float* __restrict__ bhh2,
    const float* __restrict__ fcw,  const float* __restrict__ fcb,
    float* __restrict__ h1, float* __restrict__ h2, float* __restrict__ h3,
    float* __restrict__ out)
{
    __shared__ float red[6][4];
    cg::grid_group grid = cg::this_grid();

    layer_phase<1024>(Wih0, bih0, bhh0, x,  h1, red);
    grid.sync();
    layer_phase<2048>(Wih1, bih1, bhh1, h1, h2, red);
    grid.sync();
    layer_phase<2048>(Wih2, bih2, bhh2, h2, h3, red);
    grid.sync();

    // FC: out[0] = dot(fc_w, h3) + fc_b, block 0 only (deterministic, no atomics)
    if (blockIdx.x == 0) {
        const int t    = threadIdx.x;
        const int lane = t & 63;
        const int wv   = t >> 6;
        float acc = 0.f;
        #pragma unroll
        for (int c = 0; c < 2; ++c) {
            const int off = c * 1024 + t * 4;
            f32x4 w  = *reinterpret_cast<const f32x4*>(fcw + off);
            f32x4 hv = *reinterpret_cast<const f32x4*>(h3  + off);
            acc = fmaf(w.x, hv.x, acc); acc = fmaf(w.y, hv.y, acc);
            acc = fmaf(w.z, hv.z, acc); acc = fmaf(w.w, hv.w, acc);
        }
        #pragma unroll
        for (int m = 32; m > 0; m >>= 1) acc += __shfl_xor(acc, m, 64);
        if (lane == 0) red[0][wv] = acc;   // red safe to reuse: grid.sync barrier
        __syncthreads();
        if (t == 0)
            out[0] = red[0][0] + red[0][1] + red[0][2] + red[0][3] + fcb[0];
    }
}

extern "C" void kernel_launch(void* const* d_in, const int* in_sizes, int n_in,
                              void* d_out, int out_size, void* d_ws, size_t ws_size,
                              hipStream_t stream) {
    // setup_inputs() order (all fp32; W_hh_* dead since h0=0):
    // 0:x 1:W_ih_0 2:W_hh_0 3:b_ih_0 4:b_hh_0
    // 5:W_ih_1 6:W_hh_1 7:b_ih_1 8:b_hh_1
    // 9:W_ih_2 10:W_hh_2 11:b_ih_2 12:b_hh_2
    // 13:fc_w 14:fc_b
    const float* x    = (const float*)d_in[0];
    const float* Wih0 = (const float*)d_in[1];
    const float* bih0 = (const float*)d_in[3];
    const float* bhh0 = (const float*)d_in[4];
    const float* Wih1 = (const float*)d_in[5];
    const float* bih1 = (const float*)d_in[7];
    const float* bhh1 = (const float*)d_in[8];
    const float* Wih2 = (const float*)d_in[9];
    const float* bih2 = (const float*)d_in[11];
    const float* bhh2 = (const float*)d_in[12];
    const float* fcw  = (const float*)d_in[13];
    const float* fcb  = (const float*)d_in[14];

    float* h1  = (float*)d_ws;       // [HID] fp32
    float* h2  = h1 + HID;
    float* h3  = h2 + HID;
    float* out = (float*)d_out;

    void* args[] = {
        (void*)&x,
        (void*)&Wih0, (void*)&bih0, (void*)&bhh0,
        (void*)&Wih1, (void*)&bih1, (void*)&bhh1,
        (void*)&Wih2, (void*)&bih2, (void*)&bhh2,
        (void*)&fcw,  (void*)&fcb,
        (void*)&h1,   (void*)&h2,   (void*)&h3,
        (void*)&out
    };
    hipLaunchCooperativeKernel(reinterpret_cast<void*>(&fused_lstm),
                               dim3(NBLK), dim3(256), args, 0, stream);
}

// Round 4
// 32.309 us; speedup vs baseline: 9.8376x; 9.8376x over previous
//
#include <hip/hip_runtime.h>

#define HID 2048

typedef __attribute__((ext_vector_type(4))) float f32x4;

__device__ __forceinline__ float sigmoidf_(float x) {
    return 1.0f / (1.0f + __expf(-x));
}

// One 256-thread block per output neuron j in [0, HID).
// h0 = c0 = 0  =>  W_hh unused, f-gate dead:
//   h[j] = sigmoid(g_o) * tanh( sigmoid(g_i) * tanh(g_g) )
// All global loads for the block's work are issued as one independent batch
// (U*4 dwordx4 per thread) before any FMA -> max memory-level parallelism.
template <int K>
__global__ __launch_bounds__(256) void lstm_layer_kernel(
    const float* __restrict__ W,     // [4*HID, K] fp32
    const float* __restrict__ b_ih,  // [4*HID] fp32
    const float* __restrict__ b_hh,  // [4*HID] fp32
    const float* __restrict__ x,     // [K] fp32
    float* __restrict__ h_out)       // [HID] fp32
{
    const int t    = threadIdx.x;
    const int lane = t & 63;
    const int wv   = t >> 6;
    const int j    = blockIdx.x;

    const float* ri = W + (size_t)j * K;                // i-gate row
    const float* rg = W + (size_t)(j + 2 * HID) * K;    // g-gate row
    const float* ro = W + (size_t)(j + 3 * HID) * K;    // o-gate row

    // uniform (s_load) bias prefetch, issued before the vector loads
    const float Bi = b_ih[j]           + b_hh[j];
    const float Bg = b_ih[j + 2 * HID] + b_hh[j + 2 * HID];
    const float Bo = b_ih[j + 3 * HID] + b_hh[j + 3 * HID];

    constexpr int U = K / 1024;       // chunks of 1024 floats (1 for L0, 2 else)
    f32x4 xv[U], wi[U], wg[U], wo[U];
    #pragma unroll
    for (int u = 0; u < U; ++u) {
        const int off = u * 1024 + t * 4;               // 16B/lane, coalesced
        xv[u] = *reinterpret_cast<const f32x4*>(x  + off);
        wi[u] = *reinterpret_cast<const f32x4*>(ri + off);
        wg[u] = *reinterpret_cast<const f32x4*>(rg + off);
        wo[u] = *reinterpret_cast<const f32x4*>(ro + off);
    }

    float ai = 0.f, ag = 0.f, ao = 0.f;
    #pragma unroll
    for (int u = 0; u < U; ++u) {
        ai = fmaf(wi[u].x, xv[u].x, ai); ai = fmaf(wi[u].y, xv[u].y, ai);
        ai = fmaf(wi[u].z, xv[u].z, ai); ai = fmaf(wi[u].w, xv[u].w, ai);
        ag = fmaf(wg[u].x, xv[u].x, ag); ag = fmaf(wg[u].y, xv[u].y, ag);
        ag = fmaf(wg[u].z, xv[u].z, ag); ag = fmaf(wg[u].w, xv[u].w, ag);
        ao = fmaf(wo[u].x, xv[u].x, ao); ao = fmaf(wo[u].y, xv[u].y, ao);
        ao = fmaf(wo[u].z, xv[u].z, ao); ao = fmaf(wo[u].w, xv[u].w, ao);
    }

    // wave64 butterfly, then cross-wave via LDS
    #pragma unroll
    for (int m = 32; m > 0; m >>= 1) {
        ai += __shfl_xor(ai, m, 64);
        ag += __shfl_xor(ag, m, 64);
        ao += __shfl_xor(ao, m, 64);
    }

    __shared__ float red[3][4];
    if (lane == 0) { red[0][wv] = ai; red[1][wv] = ag; red[2][wv] = ao; }
    __syncthreads();

    if (t == 0) {
        const float gi = red[0][0] + red[0][1] + red[0][2] + red[0][3] + Bi;
        const float gg = red[1][0] + red[1][1] + red[1][2] + red[1][3] + Bg;
        const float go = red[2][0] + red[2][1] + red[2][2] + red[2][3] + Bo;
        h_out[j] = sigmoidf_(go) * tanhf(sigmoidf_(gi) * tanhf(gg));
    }
}

// out[0] = dot(fc_w, h) + fc_b   (OUT_DIM == 1), all fp32
__global__ __launch_bounds__(256) void fc_kernel(
    const float* __restrict__ fc_w,  // [HID]
    const float* __restrict__ fc_b,  // [1]
    const float* __restrict__ h,     // [HID]
    float* __restrict__ out)         // [1]
{
    const int t    = threadIdx.x;
    const int lane = t & 63;
    const int wv   = t >> 6;

    f32x4 w0  = *reinterpret_cast<const f32x4*>(fc_w + t * 4);
    f32x4 w1  = *reinterpret_cast<const f32x4*>(fc_w + 1024 + t * 4);
    f32x4 hv0 = *reinterpret_cast<const f32x4*>(h    + t * 4);
    f32x4 hv1 = *reinterpret_cast<const f32x4*>(h    + 1024 + t * 4);

    float acc = 0.f;
    acc = fmaf(w0.x, hv0.x, acc); acc = fmaf(w0.y, hv0.y, acc);
    acc = fmaf(w0.z, hv0.z, acc); acc = fmaf(w0.w, hv0.w, acc);
    acc = fmaf(w1.x, hv1.x, acc); acc = fmaf(w1.y, hv1.y, acc);
    acc = fmaf(w1.z, hv1.z, acc); acc = fmaf(w1.w, hv1.w, acc);

    #pragma unroll
    for (int m = 32; m > 0; m >>= 1) acc += __shfl_xor(acc, m, 64);

    __shared__ float red[4];
    if (lane == 0) red[wv] = acc;
    __syncthreads();
    if (t == 0) out[0] = red[0] + red[1] + red[2] + red[3] + fc_b[0];
}

extern "C" void kernel_launch(void* const* d_in, const int* in_sizes, int n_in,
                              void* d_out, int out_size, void* d_ws, size_t ws_size,
                              hipStream_t stream) {
    // setup_inputs() order (all fp32; W_hh_* dead since h0=0):
    // 0:x 1:W_ih_0 2:W_hh_0 3:b_ih_0 4:b_hh_0
    // 5:W_ih_1 6:W_hh_1 7:b_ih_1 8:b_hh_1
    // 9:W_ih_2 10:W_hh_2 11:b_ih_2 12:b_hh_2
    // 13:fc_w 14:fc_b
    const float* x    = (const float*)d_in[0];
    const float* Wih0 = (const float*)d_in[1];
    const float* bih0 = (const float*)d_in[3];
    const float* bhh0 = (const float*)d_in[4];
    const float* Wih1 = (const float*)d_in[5];
    const float* bih1 = (const float*)d_in[7];
    const float* bhh1 = (const float*)d_in[8];
    const float* Wih2 = (const float*)d_in[9];
    const float* bih2 = (const float*)d_in[11];
    const float* bhh2 = (const float*)d_in[12];
    const float* fcw  = (const float*)d_in[13];
    const float* fcb  = (const float*)d_in[14];

    float* h1 = (float*)d_ws;        // [HID] fp32
    float* h2 = h1 + HID;
    float* h3 = h2 + HID;

    lstm_layer_kernel<1024><<<HID, 256, 0, stream>>>(Wih0, bih0, bhh0, x,  h1);
    lstm_layer_kernel<2048><<<HID, 256, 0, stream>>>(Wih1, bih1, bhh1, h1, h2);
    lstm_layer_kernel<2048><<<HID, 256, 0, stream>>>(Wih2, bih2, bhh2, h2, h3);
    fc_kernel<<<1, 256, 0, stream>>>(fcw, fcb, h3, (float*)d_out);
}